// Round 9
// baseline (148.710 us; speedup 1.0000x reference)
//
#include <hip/hip_runtime.h>
#include <hip/hip_bf16.h>

// out[b,o] = sum_i x[b,i]*w[o,i] + bias[o]; M=4096, N=2048, K=2048, fp32 io.
// R9: BARRIER-FREE GEMM. R3/R6/R8 all plateau at ~42us (819 TF) regardless of
// LDS traffic -> the binder is the per-iter vmcnt(0)+s_barrier drain (m97
// plateau, m131-141: inexpressible fix within a barriered K-loop). Escape:
// cvt pre-swizzles BOTH x and w into MFMA fragment-major layout (1KB per
// 16x32 fragment, lane-ordered); GEMM reads A- and B-frags directly from
// global (coalesced dwordx4, wave-uniform base + lane*16) into VGPRs.
// No LDS, no __syncthreads -> compiler software-pipelines with vmcnt(N).
// Per-iter unique bytes 32KB (fits L1); wave-duplicated reads are
// same-address -> L1/L2 broadcast. XCD swizzle keeps per-XCD slabs L2-sized.

#define M_DIM 4096
#define N_DIM 2048
#define K_DIM 2048

typedef unsigned short ushort_t;
typedef __attribute__((ext_vector_type(8))) short short8;      // 8 bf16 (A/B frag)
typedef __attribute__((ext_vector_type(4))) float float4v;     // C/D frag
typedef __attribute__((ext_vector_type(8))) unsigned short ushort8;

__device__ __forceinline__ unsigned short f2bf_rne(float f) {
    unsigned int u = __builtin_bit_cast(unsigned int, f);
    u += 0x7FFFu + ((u >> 16) & 1u);
    return (unsigned short)(u >> 16);
}

// Fragment-major layout: frag (t, kt) holds src[t*16 + lrow][kt*32 + quad*8 + e]
// at ushort offset ((t*64 + kt)*64 + quad*16 + lrow)*8 + e.   (64 kt per row-tile)
// A: t = m-tile (256), B: t = n-tile (128). Same A-operand/B-operand layout
// verified in R8 (B) and R1-R8 (A via LDS row reads).
#define XBLK 4096   // x: 8.39M elems / 8 / 256
#define WBLK 2048   // w: 4.19M elems / 8 / 256

__global__ void __launch_bounds__(256) cvt_both(const float* __restrict__ x,
                                                const float* __restrict__ w,
                                                ushort_t* __restrict__ afrag,
                                                ushort_t* __restrict__ wfrag) {
    const int b = blockIdx.x;
    const bool isX = (b < XBLK);
    const int t    = (isX ? b : b - XBLK) * 256 + threadIdx.x;
    const int lrow = t & 15;
    const int quad = (t >> 4) & 3;
    const int kt   = (t >> 6) & 63;
    const int rt   = t >> 12;               // m-tile or n-tile
    const float* src = (isX ? x : w) + (long long)(rt * 16 + lrow) * K_DIM + kt * 32 + quad * 8;
    float4v a = *(const float4v*)(src);
    float4v c = *(const float4v*)(src + 4);
    ushort8 r;
    r[0] = f2bf_rne(a[0]); r[1] = f2bf_rne(a[1]);
    r[2] = f2bf_rne(a[2]); r[3] = f2bf_rne(a[3]);
    r[4] = f2bf_rne(c[0]); r[5] = f2bf_rne(c[1]);
    r[6] = f2bf_rne(c[2]); r[7] = f2bf_rne(c[3]);
    ushort_t* dst = isX ? afrag : wfrag;
    ((ushort8*)dst)[(size_t)((rt * 64 + kt) * 64) + (t & 63)] = r;   // coalesced
}

// ---------------- barrier-free MFMA GEMM, C = A * B^T + bias ----------------
// Block: 128x128 tile, 512 threads = 8 waves in 2(row) x 4(col); wave-tile 64x32.
// All operands fragment-major direct from global. No LDS, no barriers.
__global__ void __launch_bounds__(512, 4) gemm_direct(const ushort_t* __restrict__ afrag,
                                                      const ushort_t* __restrict__ wfrag,
                                                      const float* __restrict__ bias,
                                                      float* __restrict__ out) {
    const int tid  = threadIdx.x;
    const int wave = tid >> 6;
    const int lane = tid & 63;
    const int quad = lane >> 4;    // 0..3
    const int lrow = lane & 15;    // 0..15

    // XCD swizzle: 64 blocks/XCD form an 8(bm) x 8(bn) region.
    const int xcd = blockIdx.x & 7;
    const int idx = blockIdx.x >> 3;              // 0..63
    const int bm  = (xcd & 3) * 8 + (idx & 7);    // 0..31
    const int bn  = (xcd >> 2) * 8 + (idx >> 3);  // 0..15
    const int rowBase = bm * 128;
    const int colBase = bn * 128;

    const int waveR = (wave >> 2) * 64;   // 0 or 64
    const int waveC = (wave & 3) * 32;    // 0,32,64,96

    const int mt0 = (rowBase + waveR) >> 4;   // 4 consecutive m-tiles
    const int nt0 = (colBase + waveC) >> 4;   // 2 consecutive n-tiles

    // Per-tile fragment pointers; frag (rt,kt) at (rt*64+kt)*512 ushorts.
    // Advance by 2 frags (BK=64 = 2 k-tiles) per iteration.
    const ushort_t* aP0 = afrag + ((long long)(mt0 + 0) * 64) * 512 + lane * 8;
    const ushort_t* aP1 = afrag + ((long long)(mt0 + 1) * 64) * 512 + lane * 8;
    const ushort_t* aP2 = afrag + ((long long)(mt0 + 2) * 64) * 512 + lane * 8;
    const ushort_t* aP3 = afrag + ((long long)(mt0 + 3) * 64) * 512 + lane * 8;
    const ushort_t* bP0 = wfrag + ((long long)(nt0 + 0) * 64) * 512 + lane * 8;
    const ushort_t* bP1 = wfrag + ((long long)(nt0 + 1) * 64) * 512 + lane * 8;

    float4v acc[4][2] = {};

#pragma unroll 2
    for (int it = 0; it < 32; ++it) {
        short8 a00 = *(const short8*)(aP0);
        short8 a01 = *(const short8*)(aP0 + 512);
        short8 a10 = *(const short8*)(aP1);
        short8 a11 = *(const short8*)(aP1 + 512);
        short8 a20 = *(const short8*)(aP2);
        short8 a21 = *(const short8*)(aP2 + 512);
        short8 a30 = *(const short8*)(aP3);
        short8 a31 = *(const short8*)(aP3 + 512);
        short8 b00 = *(const short8*)(bP0);
        short8 b01 = *(const short8*)(bP0 + 512);
        short8 b10 = *(const short8*)(bP1);
        short8 b11 = *(const short8*)(bP1 + 512);
        aP0 += 1024; aP1 += 1024; aP2 += 1024; aP3 += 1024;
        bP0 += 1024; bP1 += 1024;

        acc[0][0] = __builtin_amdgcn_mfma_f32_16x16x32_bf16(a00, b00, acc[0][0], 0, 0, 0);
        acc[1][0] = __builtin_amdgcn_mfma_f32_16x16x32_bf16(a10, b00, acc[1][0], 0, 0, 0);
        acc[2][0] = __builtin_amdgcn_mfma_f32_16x16x32_bf16(a20, b00, acc[2][0], 0, 0, 0);
        acc[3][0] = __builtin_amdgcn_mfma_f32_16x16x32_bf16(a30, b00, acc[3][0], 0, 0, 0);
        acc[0][1] = __builtin_amdgcn_mfma_f32_16x16x32_bf16(a00, b10, acc[0][1], 0, 0, 0);
        acc[1][1] = __builtin_amdgcn_mfma_f32_16x16x32_bf16(a10, b10, acc[1][1], 0, 0, 0);
        acc[2][1] = __builtin_amdgcn_mfma_f32_16x16x32_bf16(a20, b10, acc[2][1], 0, 0, 0);
        acc[3][1] = __builtin_amdgcn_mfma_f32_16x16x32_bf16(a30, b10, acc[3][1], 0, 0, 0);
        acc[0][0] = __builtin_amdgcn_mfma_f32_16x16x32_bf16(a01, b01, acc[0][0], 0, 0, 0);
        acc[1][0] = __builtin_amdgcn_mfma_f32_16x16x32_bf16(a11, b01, acc[1][0], 0, 0, 0);
        acc[2][0] = __builtin_amdgcn_mfma_f32_16x16x32_bf16(a21, b01, acc[2][0], 0, 0, 0);
        acc[3][0] = __builtin_amdgcn_mfma_f32_16x16x32_bf16(a31, b01, acc[3][0], 0, 0, 0);
        acc[0][1] = __builtin_amdgcn_mfma_f32_16x16x32_bf16(a01, b11, acc[0][1], 0, 0, 0);
        acc[1][1] = __builtin_amdgcn_mfma_f32_16x16x32_bf16(a11, b11, acc[1][1], 0, 0, 0);
        acc[2][1] = __builtin_amdgcn_mfma_f32_16x16x32_bf16(a21, b11, acc[2][1], 0, 0, 0);
        acc[3][1] = __builtin_amdgcn_mfma_f32_16x16x32_bf16(a31, b11, acc[3][1], 0, 0, 0);
    }

    // ---- epilogue: C/D layout col=lane&15, row=quad*4+reg ----
#pragma unroll
    for (int ni = 0; ni < 2; ni++) {
        const int col = colBase + waveC + ni * 16 + lrow;
        const float bv = bias[col];
#pragma unroll
        for (int mi = 0; mi < 4; mi++) {
            const int row0 = rowBase + waveR + mi * 16 + quad * 4;
            float4v v = acc[mi][ni];
#pragma unroll
            for (int i = 0; i < 4; i++)
                out[(long long)(row0 + i) * N_DIM + col] = v[i] + bv;
        }
    }
}

// ---------------- fallback (ws too small): fp32 naive ----------------
__global__ void __launch_bounds__(256) linear_naive(const float* __restrict__ x,
                                                    const float* __restrict__ w,
                                                    const float* __restrict__ bias,
                                                    float* __restrict__ out) {
    __shared__ float xs[K_DIM];
    const int b = blockIdx.y;
    const int o = blockIdx.x * 256 + threadIdx.x;
    for (int k = threadIdx.x; k < K_DIM; k += 256)
        xs[k] = x[(long long)b * K_DIM + k];
    __syncthreads();
    const float4v* wr = (const float4v*)(w + (long long)o * K_DIM);
    float s = 0.f;
    for (int k4 = 0; k4 < K_DIM / 4; k4++) {
        float4v wv = wr[k4];
        float4v xv = *(const float4v*)&xs[k4 * 4];
        s += xv[0] * wv[0] + xv[1] * wv[1] + xv[2] * wv[2] + xv[3] * wv[3];
    }
    out[(long long)b * N_DIM + o] = s + bias[o];
}

extern "C" void kernel_launch(void* const* d_in, const int* in_sizes, int n_in,
                              void* d_out, int out_size, void* d_ws, size_t ws_size,
                              hipStream_t stream) {
    const float* x    = (const float*)d_in[0];   // [4096, 2048]
    const float* w    = (const float*)d_in[1];   // [2048, 2048]
    const float* bias = (const float*)d_in[2];   // [2048]
    float* out = (float*)d_out;                  // [4096, 2048]

    const size_t xElems = (size_t)M_DIM * K_DIM;   // 8388608
    const size_t wElems = (size_t)N_DIM * K_DIM;   // 4194304
    const size_t need = (xElems + wElems) * sizeof(ushort_t);  // ~25.2 MB

    if (ws_size >= need) {
        ushort_t* afrag = (ushort_t*)d_ws;
        ushort_t* wfrag = afrag + xElems;
        cvt_both<<<XBLK + WBLK, 256, 0, stream>>>(x, w, afrag, wfrag);
        gemm_direct<<<(M_DIM / 128) * (N_DIM / 128), 512, 0, stream>>>(afrag, wfrag, bias, out);
    } else {
        dim3 grid(N_DIM / 256, M_DIM);
        linear_naive<<<grid, 256, 0, stream>>>(x, w, bias, out);
    }
}

// Round 10
// 132.032 us; speedup vs baseline: 1.1263x; 1.1263x over previous
//
#include <hip/hip_runtime.h>
#include <hip/hip_bf16.h>

// out[b,o] = sum_i x[b,i]*w[o,i] + bias[o]; M=4096, N=2048, K=2048, fp32 io.
// R10: REVERT to R6 — the measured optimum (total 130.5us: cvt 13 + gemm 42
// + ~75 fixed harness). Nine rounds established three regimes:
//  (a) ~42us structural plateau (R3/R6/R8): invariant under LDS traffic,
//      barrier count, and staging mix — the m97 vmcnt(0)+barrier limit,
//      not fixable at HIP level (m131-m141).
//  (b) L2-BW-bound when LDS dedup removed (R9: 60us, 96KB raw vs 32KB unique).
//  (c) VALU/latency-bound: fused cvt (R7: 105+), 8 waves/CU (R4: 46),
//      split-K atomics (R5: 86).
// Config: 512thr, 8 waves x 64x32 wave-tiles, 128x128 tile, BK=128,
// grid 512 = 2 blocks/CU, XOR-swizzled LDS (conflict-free),
// global_load_lds width=16 staging, 16x16x32 bf16 MFMA.

#define M_DIM 4096
#define N_DIM 2048
#define K_DIM 2048
#define BK 128

typedef unsigned short ushort_t;
typedef __attribute__((ext_vector_type(8))) short short8;      // 8 bf16 (A/B frag)
typedef __attribute__((ext_vector_type(4))) float float4v;     // C/D frag
typedef __attribute__((ext_vector_type(8))) unsigned short ushort8;

// ---------------- fp32 -> bf16 (RNE), x and w fused in one launch ----------------
__device__ __forceinline__ unsigned short f2bf_rne(float f) {
    unsigned int u = __builtin_bit_cast(unsigned int, f);
    u += 0x7FFFu + ((u >> 16) & 1u);
    return (unsigned short)(u >> 16);
}

__global__ void __launch_bounds__(256) cvt_both(const float* __restrict__ x,
                                                const float* __restrict__ w,
                                                ushort8* __restrict__ ws8,
                                                int xN8, int totN8) {
    int idx = blockIdx.x * 256 + threadIdx.x;
    if (idx >= totN8) return;
    const float4v* in4 = (idx < xN8) ? (const float4v*)x + (size_t)idx * 2
                                     : (const float4v*)w + (size_t)(idx - xN8) * 2;
    float4v a = in4[0];
    float4v b = in4[1];
    ushort8 r;
    r[0] = f2bf_rne(a[0]); r[1] = f2bf_rne(a[1]);
    r[2] = f2bf_rne(a[2]); r[3] = f2bf_rne(a[3]);
    r[4] = f2bf_rne(b[0]); r[5] = f2bf_rne(b[1]);
    r[6] = f2bf_rne(b[2]); r[7] = f2bf_rne(b[3]);
    ws8[idx] = r;
}

// ---------------- async global -> LDS (16B per lane; dest = base + lane*16) ----
__device__ __forceinline__ void async_load16(const void* g, void* l) {
    __builtin_amdgcn_global_load_lds(
        (const __attribute__((address_space(1))) void*)(g),
        (__attribute__((address_space(3))) void*)(l), 16, 0, 0);
}

// ---------------- bf16 MFMA GEMM, C = Xb * Wb^T + bias ----------------
// Xb: [M,K] bf16 row-major, Wb: [N,K] bf16 row-major.
// Block: 128x128 tile, 512 threads = 8 waves in 2(row) x 4(col); wave-tile 64x32.
__global__ void __launch_bounds__(512) gemm_bf16(const ushort_t* __restrict__ xb,
                                                 const ushort_t* __restrict__ wb,
                                                 const float* __restrict__ bias,
                                                 float* __restrict__ out) {
    __shared__ ushort_t ldsA[128 * BK];   // 32 KB
    __shared__ ushort_t ldsB[128 * BK];   // 32 KB

    const int tid  = threadIdx.x;
    const int wave = tid >> 6;
    const int lane = tid & 63;
    const int quad = lane >> 4;    // 0..3
    const int lrow = lane & 15;    // 0..15

    const int bm = blockIdx.x >> 4;    // 0..31
    const int bn = blockIdx.x & 15;    // 0..15
    const int rowBase = bm * 128;
    const int colBase = bn * 128;

    const int waveR = (wave >> 2) * 64;   // 0 or 64
    const int waveC = (wave & 3) * 32;    // 0,32,64,96

    // ---- staging: waves 0-3 stage A rows sgrp*32..+31, waves 4-7 stage B ----
    // Rows are 256B = 16 chunks of 16B; one instr covers 4 rows.
    // HW places lane L at row_local L>>4, position L&15. Stored chunk at
    // position p of row r is p ^ (r&15), so instr j (rows R0+4j..+3) lane L
    // fetches global chunk q = (L&15) ^ (L>>4) ^ ((4j)&15).
    const int  sgrp = wave & 3;
    const bool isB  = wave >= 4;
    const int  R0   = sgrp * 32;
    const int  rowl = lane >> 4;          // 0..3
    const int  qb   = (lane & 15) ^ rowl;
    const ushort_t* src = isB ? wb + (long long)colBase * K_DIM
                              : xb + (long long)rowBase * K_DIM;
    const ushort_t* g[8];
#pragma unroll
    for (int j = 0; j < 8; j++)
        g[j] = src + (long long)(R0 + 4 * j + rowl) * K_DIM + (qb ^ ((4 * j) & 15)) * 8;
    ushort_t* lbase = (isB ? ldsB : ldsA) + R0 * BK;  // wave-uniform

    // ---- fragment read offsets ----
    // Row r = waveR/C + mi*16 + lrow -> r&15 = lrow. Chunk c = kc*4 + quad,
    // stored at (kc*4 ^ quad ^ lrow); ushort offset = that * 8 = sw ^ (kc*32).
    const int sw = (quad ^ lrow) * 8;
    const ushort_t* aP = &ldsA[(waveR + lrow) * BK];
    const ushort_t* bP = &ldsB[(waveC + lrow) * BK];

    float4v acc[4][2] = {};

    for (int k0 = 0; k0 < K_DIM; k0 += BK) {
#pragma unroll
        for (int j = 0; j < 8; j++) {
            async_load16(g[j], lbase + (4 * j) * BK);
            g[j] += BK;
        }
        __syncthreads();

#pragma unroll
        for (int kc = 0; kc < 4; kc++) {
            const int ko = sw ^ (kc * 32);
            short8 af[4], bf[2];
#pragma unroll
            for (int mi = 0; mi < 4; mi++)
                af[mi] = *(const short8*)(aP + mi * 16 * BK + ko);
#pragma unroll
            for (int ni = 0; ni < 2; ni++)
                bf[ni] = *(const short8*)(bP + ni * 16 * BK + ko);
#pragma unroll
            for (int mi = 0; mi < 4; mi++)
#pragma unroll
                for (int ni = 0; ni < 2; ni++)
                    acc[mi][ni] = __builtin_amdgcn_mfma_f32_16x16x32_bf16(
                        af[mi], bf[ni], acc[mi][ni], 0, 0, 0);
        }
        __syncthreads();
    }

    // ---- epilogue: C/D layout col=lane&15, row=quad*4+reg ----
#pragma unroll
    for (int ni = 0; ni < 2; ni++) {
        const int col = colBase + waveC + ni * 16 + lrow;
        const float bv = bias[col];
#pragma unroll
        for (int mi = 0; mi < 4; mi++) {
            const int row0 = rowBase + waveR + mi * 16 + quad * 4;
            float4v v = acc[mi][ni];
#pragma unroll
            for (int i = 0; i < 4; i++)
                out[(long long)(row0 + i) * N_DIM + col] = v[i] + bv;
        }
    }
}

// ---------------- fallback (ws too small): fp32 naive ----------------
__global__ void __launch_bounds__(256) linear_naive(const float* __restrict__ x,
                                                    const float* __restrict__ w,
                                                    const float* __restrict__ bias,
                                                    float* __restrict__ out) {
    __shared__ float xs[K_DIM];
    const int b = blockIdx.y;
    const int o = blockIdx.x * 256 + threadIdx.x;
    for (int k = threadIdx.x; k < K_DIM; k += 256)
        xs[k] = x[(long long)b * K_DIM + k];
    __syncthreads();
    const float4v* wr = (const float4v*)(w + (long long)o * K_DIM);
    float s = 0.f;
    for (int k4 = 0; k4 < K_DIM / 4; k4++) {
        float4v wv = wr[k4];
        float4v xv = *(const float4v*)&xs[k4 * 4];
        s += xv[0] * wv[0] + xv[1] * wv[1] + xv[2] * wv[2] + xv[3] * wv[3];
    }
    out[(long long)b * N_DIM + o] = s + bias[o];
}

extern "C" void kernel_launch(void* const* d_in, const int* in_sizes, int n_in,
                              void* d_out, int out_size, void* d_ws, size_t ws_size,
                              hipStream_t stream) {
    const float* x    = (const float*)d_in[0];   // [4096, 2048]
    const float* w    = (const float*)d_in[1];   // [2048, 2048]
    const float* bias = (const float*)d_in[2];   // [2048]
    float* out = (float*)d_out;                  // [4096, 2048]

    const size_t xElems = (size_t)M_DIM * K_DIM;   // 8388608
    const size_t wElems = (size_t)N_DIM * K_DIM;   // 4194304
    const size_t need = (xElems + wElems) * sizeof(ushort_t);  // ~25.2 MB

    if (ws_size >= need) {
        ushort_t* xb = (ushort_t*)d_ws;
        ushort_t* wb = xb + xElems;
        const int xN8 = (int)(xElems / 8);
        const int totN8 = (int)((xElems + wElems) / 8);
        cvt_both<<<(totN8 + 255) / 256, 256, 0, stream>>>(x, w, (ushort8*)d_ws, xN8, totN8);
        gemm_bf16<<<(M_DIM / 128) * (N_DIM / 128), 512, 0, stream>>>(xb, wb, bias, out);
    } else {
        dim3 grid(N_DIM / 256, M_DIM);
        linear_naive<<<grid, 256, 0, stream>>>(x, w, bias, out);
    }
}